// Round 17
// baseline (283.073 us; speedup 1.0000x reference)
//
#include <hip/hip_runtime.h>
#include <hip/hip_bf16.h>

// ---- bf16 helpers ----
static __device__ __forceinline__ unsigned short f2bf(float f) {
    unsigned u = __float_as_uint(f);
    unsigned r = (u + 0x7FFF + ((u >> 16) & 1)) >> 16;
    return (unsigned short)r;
}
static __device__ __forceinline__ float bflo(unsigned v) { return __uint_as_float(v << 16); }
static __device__ __forceinline__ float bfhi(unsigned v) { return __uint_as_float(v & 0xFFFF0000u); }
static __device__ __forceinline__ unsigned pack2bf(float a, float b) {
    __hip_bfloat162 h2 = __float22bfloat162_rn(float2{a, b});
    union { __hip_bfloat162 h; unsigned u; } cv;
    cv.h = h2;
    return cv.u;
}

typedef __attribute__((ext_vector_type(8))) short bf16x8;
typedef __attribute__((ext_vector_type(8))) unsigned short u16x8;
typedef __attribute__((ext_vector_type(4))) float f32x4;

// ==================== bucket binning ====================
#define BKT_SHIFT 7
#define BKT_NODES 128
#define CHUNK 16384  // edges per hist/scatter block -> B=196 blocks

__global__ __launch_bounds__(512) void hist_wconv(const int* __restrict__ dst, int* __restrict__ histG,
                                                  const float* __restrict__ W, unsigned short* __restrict__ W1T,
                                                  int B, int NB, int E) {
    if ((int)blockIdx.x >= B) {
        int gidx = (blockIdx.x - B) * 512 + threadIdx.x;
        if (gidx < 32 * 512) {
            int c = gidx >> 9, k = gidx & 511;
            W1T[gidx] = f2bf(W[(size_t)k * 32 + c]);
        }
        return;
    }
    __shared__ int hist[1024];
    int tid = threadIdx.x;
    for (int i = tid; i < NB; i += 512) hist[i] = 0;
    __syncthreads();
    int base = blockIdx.x * CHUNK;
    for (int i = tid; i < CHUNK; i += 512) {
        int e = base + i;
        if (e >= E) break;
        atomicAdd(&hist[dst[e] >> BKT_SHIFT], 1);
    }
    __syncthreads();
    for (int i = tid; i < NB; i += 512) histG[(size_t)i * B + blockIdx.x] = hist[i];
}

__global__ __launch_bounds__(512) void scatter_k(const int* __restrict__ src, const int* __restrict__ dst,
                                                 const int* __restrict__ scanG, const int* __restrict__ blksum,
                                                 int* __restrict__ pairs, int B, int NB, int E) {
    __shared__ int sbase[1024];
    __shared__ int scnt[1024];
    int tid = threadIdx.x;
    for (int i = tid; i < NB; i += 512) {
        size_t idx = (size_t)i * B + blockIdx.x;
        sbase[i] = scanG[idx] + blksum[idx >> 11];
        scnt[i] = 0;
    }
    __syncthreads();
    int base = blockIdx.x * CHUNK;
    for (int i = tid; i < CHUNK; i += 512) {
        int e = base + i;
        if (e >= E) break;
        int d = dst[e], s = src[e];
        int b = d >> BKT_SHIFT;
        int r = atomicAdd(&scnt[b], 1);
        pairs[sbase[b] + r] = (s << BKT_SHIFT) | (d & (BKT_NODES - 1));
    }
}

// ==================== scan (exclusive), 256 thr x 8 = 2048 elems/block ====================
#define SCAN_VPT 8
#define SCAN_ELEMS 2048

__global__ __launch_bounds__(256) void scan1(const int* __restrict__ in, int* __restrict__ out,
                                             int* __restrict__ blksum, int n) {
    __shared__ int sh[256];
    int base = blockIdx.x * SCAN_ELEMS + threadIdx.x * SCAN_VPT;
    int v[SCAN_VPT];
    int sum = 0;
    #pragma unroll
    for (int j = 0; j < SCAN_VPT; ++j) {
        v[j] = (base + j < n) ? in[base + j] : 0;
        sum += v[j];
    }
    sh[threadIdx.x] = sum;
    __syncthreads();
    for (int off = 1; off < 256; off <<= 1) {
        int t = (threadIdx.x >= off) ? sh[threadIdx.x - off] : 0;
        __syncthreads();
        sh[threadIdx.x] += t;
        __syncthreads();
    }
    if (threadIdx.x == 255) blksum[blockIdx.x] = sh[255];
    int run = sh[threadIdx.x] - sum;
    #pragma unroll
    for (int j = 0; j < SCAN_VPT; ++j) {
        if (base + j < n) out[base + j] = run;
        run += v[j];
    }
}

__global__ __launch_bounds__(256) void scan2(int* __restrict__ blksum, int nb) {
    __shared__ int sh[256];
    int t = threadIdx.x;
    int v = (t < nb) ? blksum[t] : 0;
    sh[t] = v;
    __syncthreads();
    for (int off = 1; off < 256; off <<= 1) {
        int u = (t >= off) ? sh[t - off] : 0;
        __syncthreads();
        sh[t] += u;
        __syncthreads();
    }
    if (t < nb) blksum[t] = sh[t] - v;
}

// ==================== within-bucket counting sort -> CSR + deg/dis ====================
#define SORT_CAP 8192

__global__ __launch_bounds__(512) void sort_bucket(const int* __restrict__ pairs,
        const int* __restrict__ scanG, const int* __restrict__ blksum, int B, int NB,
        int* __restrict__ csr_src, int* __restrict__ node_start,
        int* __restrict__ cnt, float* __restrict__ dis, int n, int E) {
    __shared__ int keys[SORT_CAP];
    __shared__ int lcnt[BKT_NODES];
    __shared__ int lscan[BKT_NODES];
    __shared__ int lfill[BKT_NODES];
    int bkt = blockIdx.x, tid = threadIdx.x;
    size_t idx0 = (size_t)bkt * B;
    int e0 = scanG[idx0] + blksum[idx0 >> 11];
    int e1 = E;
    if (bkt + 1 < NB) {
        size_t idx1 = (size_t)(bkt + 1) * B;
        e1 = scanG[idx1] + blksum[idx1 >> 11];
    }
    int m = e1 - e0;
    if (tid < BKT_NODES) { lcnt[tid] = 0; lfill[tid] = 0; }
    __syncthreads();
    for (int i = tid; i < m; i += 512) {
        int k = pairs[e0 + i];
        if (i < SORT_CAP) keys[i] = k;
        atomicAdd(&lcnt[k & (BKT_NODES - 1)], 1);
    }
    __syncthreads();
    if (tid < 64) {
        int c0 = lcnt[2 * tid], c1 = lcnt[2 * tid + 1];
        int s = c0 + c1;
        #pragma unroll
        for (int off = 1; off < 64; off <<= 1) {
            int t = __shfl_up(s, off);
            if (tid >= off) s += t;
        }
        lscan[2 * tid]     = s - c1 - c0;
        lscan[2 * tid + 1] = s - c1;
    }
    __syncthreads();
    int nb0 = bkt << BKT_SHIFT;
    if (tid < BKT_NODES && nb0 + tid < n) {
        int deg = lcnt[tid];
        node_start[nb0 + tid] = e0 + lscan[tid];
        cnt[nb0 + tid] = deg;
        dis[nb0 + tid] = rsqrtf((float)deg + 1.0f);
    }
    for (int i = tid; i < m; i += 512) {
        int k = (i < SORT_CAP) ? keys[i] : pairs[e0 + i];
        int d = k & (BKT_NODES - 1);
        int pos = lscan[d] + atomicAdd(&lfill[d], 1);
        csr_src[e0 + pos] = k >> BKT_SHIFT;
    }
}

// ==================== gemm1 (MFMA): 512->32 bf16, 128 nodes/block, 8 waves, x via LDS ====================
// x staged per 64-k chunk as bf16 in xb[128][72] (packed cvt on the way in);
// W1T bf16 staged once in wT[32][520]. Scaled write (dis ready).

__global__ __launch_bounds__(512) void gemm1_mfma(const float* __restrict__ x, const unsigned short* __restrict__ W1T,
                                                  const float* __restrict__ dis, unsigned short* __restrict__ g, int n) {
    __shared__ __attribute__((aligned(16))) unsigned short wT[32][520];
    __shared__ __attribute__((aligned(16))) unsigned short xb[128][72];
    int tid = threadIdx.x;
    int node0 = blockIdx.x * 128;

    #pragma unroll
    for (int r = 0; r < 4; ++r) {
        int u8 = tid + r * 512;            // ushort8 index 0..2047
        int c = u8 >> 6, kq = (u8 & 63) * 8;
        *(u16x8*)(&wT[c][kq]) = *(const u16x8*)(W1T + (size_t)c * 512 + kq);
    }

    int wv_ = tid >> 6;       // wave 0..7 -> 16-node sub-tile
    int lane = tid & 63;
    int mrow = lane & 15;
    int kg = lane >> 4;
    f32x4 acc0 = {0.f, 0.f, 0.f, 0.f};
    f32x4 acc1 = {0.f, 0.f, 0.f, 0.f};

    for (int k0 = 0; k0 < 512; k0 += 64) {
        __syncthreads();
        // stage x chunk: 128 nodes x 64 k, f32 -> bf16 packed; 2048 float4, 4/thread
        #pragma unroll
        for (int r = 0; r < 4; ++r) {
            int fi = tid + r * 512;
            int nd = fi >> 4, kq = (fi & 15) * 4;
            int gn = min(node0 + nd, n - 1);
            float4 xv = *(const float4*)(x + (size_t)gn * 512 + k0 + kq);
            uint2 pw;
            pw.x = pack2bf(xv.x, xv.y);
            pw.y = pack2bf(xv.z, xv.w);
            *(uint2*)(&xb[nd][kq]) = pw;
        }
        __syncthreads();
        #pragma unroll
        for (int ks = 0; ks < 2; ++ks) {
            bf16x8 a  = *(const bf16x8*)(&xb[wv_ * 16 + mrow][ks * 32 + kg * 8]);
            bf16x8 b0 = *(const bf16x8*)(&wT[mrow][k0 + ks * 32 + kg * 8]);
            bf16x8 b1 = *(const bf16x8*)(&wT[16 + mrow][k0 + ks * 32 + kg * 8]);
            acc0 = __builtin_amdgcn_mfma_f32_16x16x32_bf16(a, b0, acc0, 0, 0, 0);
            acc1 = __builtin_amdgcn_mfma_f32_16x16x32_bf16(a, b1, acc1, 0, 0, 0);
        }
    }
    // D: col = lane&15 (=mrow), row = kg*4 + j
    #pragma unroll
    for (int j = 0; j < 4; ++j) {
        int node = node0 + wv_ * 16 + kg * 4 + j;
        if (node < n) {
            float dv = dis[node];
            g[(size_t)node * 32 + mrow]      = f2bf(acc0[j] * dv);
            g[(size_t)node * 32 + 16 + mrow] = f2bf(acc1[j] * dv);
        }
    }
}

// ==================== gather1: uint2 CSR gather F=32 + fused (relu -> @W2 -> *dis) ====================

__global__ __launch_bounds__(256) void gather1(const int* __restrict__ csr_src,
        const int* __restrict__ start, const int* __restrict__ cnt,
        const unsigned short* __restrict__ g1, const float* __restrict__ dis,
        const float* __restrict__ b1, const float* __restrict__ W2,
        unsigned short* __restrict__ g2, int n) {
    __shared__ float w2t[16 * 33];
    for (int i = threadIdx.x; i < 512; i += 256) {
        int k = i >> 4, c = i & 15;
        w2t[c * 33 + k] = W2[i];
    }
    __syncthreads();
    int node = blockIdx.x * 4 + (threadIdx.x >> 6);
    if (node >= n) return;
    int lane = threadIdx.x & 63;
    int fq = lane & 7;
    int j = lane >> 3;
    int i0 = start[node], i1 = i0 + cnt[node];
    float a0 = 0.f, a1 = 0.f, a2 = 0.f, a3 = 0.f;
    int i = i0 + j;
    for (; i + 24 < i1; i += 32) {
        int s1 = csr_src[i];
        int s2 = csr_src[i + 8];
        int s3 = csr_src[i + 16];
        int s4 = csr_src[i + 24];
        uint2 v1 = *(const uint2*)(g1 + (size_t)s1 * 32 + fq * 4);
        uint2 v2 = *(const uint2*)(g1 + (size_t)s2 * 32 + fq * 4);
        uint2 v3 = *(const uint2*)(g1 + (size_t)s3 * 32 + fq * 4);
        uint2 v4 = *(const uint2*)(g1 + (size_t)s4 * 32 + fq * 4);
        a0 += bflo(v1.x) + bflo(v2.x) + bflo(v3.x) + bflo(v4.x);
        a1 += bfhi(v1.x) + bfhi(v2.x) + bfhi(v3.x) + bfhi(v4.x);
        a2 += bflo(v1.y) + bflo(v2.y) + bflo(v3.y) + bflo(v4.y);
        a3 += bfhi(v1.y) + bfhi(v2.y) + bfhi(v3.y) + bfhi(v4.y);
    }
    for (; i < i1; i += 8) {
        uint2 v = *(const uint2*)(g1 + (size_t)csr_src[i] * 32 + fq * 4);
        a0 += bflo(v.x); a1 += bfhi(v.x);
        a2 += bflo(v.y); a3 += bfhi(v.y);
    }
    #pragma unroll
    for (int m = 8; m < 64; m <<= 1) {
        a0 += __shfl_xor(a0, m); a1 += __shfl_xor(a1, m);
        a2 += __shfl_xor(a2, m); a3 += __shfl_xor(a3, m);
    }
    float dv = dis[node];
    uint2 sv = *(const uint2*)(g1 + (size_t)node * 32 + fq * 4);
    float v0 = fmaxf((a0 + bflo(sv.x)) * dv + b1[4 * fq + 0], 0.f);
    float v1f = fmaxf((a1 + bfhi(sv.x)) * dv + b1[4 * fq + 1], 0.f);
    float v2f = fmaxf((a2 + bflo(sv.y)) * dv + b1[4 * fq + 2], 0.f);
    float v3f = fmaxf((a3 + bfhi(sv.y)) * dv + b1[4 * fq + 3], 0.f);
    int c = lane & 15;
    int j3 = lane >> 4;
    float p = 0.f;
    #pragma unroll
    for (int kk = 0; kk < 8; ++kk) {
        int k = j3 * 8 + kk;
        int srcl = k >> 2;
        float xk;
        if ((kk & 3) == 0) xk = __shfl(v0, srcl);
        else if ((kk & 3) == 1) xk = __shfl(v1f, srcl);
        else if ((kk & 3) == 2) xk = __shfl(v2f, srcl);
        else xk = __shfl(v3f, srcl);
        p = fmaf(xk, w2t[c * 33 + k], p);
    }
    p += __shfl_xor(p, 16);
    p += __shfl_xor(p, 32);
    if (lane < 16) g2[(size_t)node * 16 + c] = f2bf(p * dv);
}

// ==================== gather2: uint2 CSR gather F=16 + fused (relu -> @W3 -> *dis) ====================

__global__ __launch_bounds__(256) void gather2(const int* __restrict__ csr_src,
        const int* __restrict__ start, const int* __restrict__ cnt,
        const unsigned short* __restrict__ g2, const float* __restrict__ dis,
        const float* __restrict__ b2, const float* __restrict__ W3,
        unsigned short* __restrict__ g3, int n) {
    __shared__ float w3t[16 * 17];
    if (threadIdx.x < 256) {
        int k = threadIdx.x >> 4, c = threadIdx.x & 15;
        w3t[c * 17 + k] = (c < 11) ? W3[(size_t)k * 11 + c] : 0.f;
    }
    __syncthreads();
    int node = blockIdx.x * 4 + (threadIdx.x >> 6);
    if (node >= n) return;
    int lane = threadIdx.x & 63;
    int fq = lane & 3;
    int j = lane >> 2;
    int i0 = start[node], i1 = i0 + cnt[node];
    float a0 = 0.f, a1 = 0.f, a2 = 0.f, a3 = 0.f;
    int i = i0 + j;
    for (; i + 16 < i1; i += 32) {
        int s1 = csr_src[i];
        int s2 = csr_src[i + 16];
        uint2 v1 = *(const uint2*)(g2 + (size_t)s1 * 16 + fq * 4);
        uint2 v2 = *(const uint2*)(g2 + (size_t)s2 * 16 + fq * 4);
        a0 += bflo(v1.x) + bflo(v2.x);
        a1 += bfhi(v1.x) + bfhi(v2.x);
        a2 += bflo(v1.y) + bflo(v2.y);
        a3 += bfhi(v1.y) + bfhi(v2.y);
    }
    if (i < i1) {
        uint2 v = *(const uint2*)(g2 + (size_t)csr_src[i] * 16 + fq * 4);
        a0 += bflo(v.x); a1 += bfhi(v.x);
        a2 += bflo(v.y); a3 += bfhi(v.y);
    }
    #pragma unroll
    for (int m = 4; m < 64; m <<= 1) {
        a0 += __shfl_xor(a0, m); a1 += __shfl_xor(a1, m);
        a2 += __shfl_xor(a2, m); a3 += __shfl_xor(a3, m);
    }
    float dv = dis[node];
    uint2 sv = *(const uint2*)(g2 + (size_t)node * 16 + fq * 4);
    float v0 = fmaxf((a0 + bflo(sv.x)) * dv + b2[4 * fq + 0], 0.f);
    float v1f = fmaxf((a1 + bfhi(sv.x)) * dv + b2[4 * fq + 1], 0.f);
    float v2f = fmaxf((a2 + bflo(sv.y)) * dv + b2[4 * fq + 2], 0.f);
    float v3f = fmaxf((a3 + bfhi(sv.y)) * dv + b2[4 * fq + 3], 0.f);
    int c = lane & 15;
    int j2 = lane >> 4;
    float p = 0.f;
    {
        float xk0 = __shfl(v0, j2);
        float xk1 = __shfl(v1f, j2);
        float xk2 = __shfl(v2f, j2);
        float xk3 = __shfl(v3f, j2);
        p = fmaf(xk0, w3t[c * 17 + j2 * 4 + 0], p);
        p = fmaf(xk1, w3t[c * 17 + j2 * 4 + 1], p);
        p = fmaf(xk2, w3t[c * 17 + j2 * 4 + 2], p);
        p = fmaf(xk3, w3t[c * 17 + j2 * 4 + 3], p);
    }
    p += __shfl_xor(p, 16);
    p += __shfl_xor(p, 32);
    if (lane < 16) g3[(size_t)node * 16 + c] = f2bf(p * dv);
}

// ==================== gather3: uint2 F=16 gather + self + bias + log_softmax ====================

__global__ __launch_bounds__(256) void gather3(const int* __restrict__ csr_src,
        const int* __restrict__ start, const int* __restrict__ cnt,
        const unsigned short* __restrict__ g, const float* __restrict__ dis,
        const float* __restrict__ bias, float* __restrict__ out, int n) {
    int node = blockIdx.x * 4 + (threadIdx.x >> 6);
    if (node >= n) return;
    int lane = threadIdx.x & 63;
    int fq = lane & 3;
    int j = lane >> 2;
    int i0 = start[node], i1 = i0 + cnt[node];
    float a0 = 0.f, a1 = 0.f, a2 = 0.f, a3 = 0.f;
    int i = i0 + j;
    for (; i + 16 < i1; i += 32) {
        int s1 = csr_src[i];
        int s2 = csr_src[i + 16];
        uint2 v1 = *(const uint2*)(g + (size_t)s1 * 16 + fq * 4);
        uint2 v2 = *(const uint2*)(g + (size_t)s2 * 16 + fq * 4);
        a0 += bflo(v1.x) + bflo(v2.x);
        a1 += bfhi(v1.x) + bfhi(v2.x);
        a2 += bflo(v1.y) + bflo(v2.y);
        a3 += bfhi(v1.y) + bfhi(v2.y);
    }
    if (i < i1) {
        uint2 v = *(const uint2*)(g + (size_t)csr_src[i] * 16 + fq * 4);
        a0 += bflo(v.x); a1 += bfhi(v.x);
        a2 += bflo(v.y); a3 += bfhi(v.y);
    }
    #pragma unroll
    for (int m = 4; m < 64; m <<= 1) {
        a0 += __shfl_xor(a0, m); a1 += __shfl_xor(a1, m);
        a2 += __shfl_xor(a2, m); a3 += __shfl_xor(a3, m);
    }
    float dvn = dis[node];
    uint2 sv = *(const uint2*)(g + (size_t)node * 16 + fq * 4);
    int f0 = 4 * fq;
    bool ok0 = f0 + 0 < 11, ok1 = f0 + 1 < 11, ok2 = f0 + 2 < 11, ok3 = f0 + 3 < 11;
    float v0 = (a0 + bflo(sv.x)) * dvn + (ok0 ? bias[f0 + 0] : 0.f);
    float v1f = (a1 + bfhi(sv.x)) * dvn + (ok1 ? bias[f0 + 1] : 0.f);
    float v2f = (a2 + bflo(sv.y)) * dvn + (ok2 ? bias[f0 + 2] : 0.f);
    float v3f = (a3 + bfhi(sv.y)) * dvn + (ok3 ? bias[f0 + 3] : 0.f);
    const float NEG = -3.0e38f;
    float m0 = fmaxf(fmaxf(ok0 ? v0 : NEG, ok1 ? v1f : NEG),
                     fmaxf(ok2 ? v2f : NEG, ok3 ? v3f : NEG));
    m0 = fmaxf(m0, __shfl_xor(m0, 1));
    m0 = fmaxf(m0, __shfl_xor(m0, 2));
    float s = (ok0 ? __expf(v0 - m0) : 0.f) + (ok1 ? __expf(v1f - m0) : 0.f)
            + (ok2 ? __expf(v2f - m0) : 0.f) + (ok3 ? __expf(v3f - m0) : 0.f);
    s += __shfl_xor(s, 1);
    s += __shfl_xor(s, 2);
    float ls = __logf(s) + m0;
    if (lane < 4) {
        float* orow = out + (size_t)node * 11 + f0;
        if (ok0) orow[0] = v0 - ls;
        if (ok1) orow[1] = v1f - ls;
        if (ok2) orow[2] = v2f - ls;
        if (ok3) orow[3] = v3f - ls;
    }
}

// ==================== launch ====================

extern "C" void kernel_launch(void* const* d_in, const int* in_sizes, int n_in,
                              void* d_out, int out_size, void* d_ws, size_t ws_size,
                              hipStream_t stream) {
    const float* x  = (const float*)d_in[0];
    const int*   ei = (const int*)d_in[1];
    const float* W1 = (const float*)d_in[2];
    const float* b1 = (const float*)d_in[3];
    const float* W2 = (const float*)d_in[4];
    const float* b2 = (const float*)d_in[5];
    const float* W3 = (const float*)d_in[6];
    const float* b3 = (const float*)d_in[7];
    float* out = (float*)d_out;

    const int n = in_sizes[0] / 512;
    const int E = in_sizes[1] / 2;
    const int* src = ei;
    const int* dst = ei + E;

    const int NB = (n + BKT_NODES - 1) >> BKT_SHIFT;      // 782
    const int B  = (E + CHUNK - 1) / CHUNK;               // 196
    const int NBB = NB * B;
    const int nb_scan = (NBB + SCAN_ELEMS - 1) / SCAN_ELEMS;

    // workspace layout (4B elements)
    int* ws0 = (int*)d_ws;
    size_t off = 0;
    int*   cnt     = ws0 + off; off += (size_t)n;
    float* dis     = (float*)(ws0 + off); off += (size_t)n;
    int*   nstart  = ws0 + off; off += (size_t)n;
    int*   scanG   = ws0 + off; off += (size_t)NBB;
    int*   blksum  = ws0 + off; off += 256;
    int*   pairs   = ws0 + off; off += (size_t)E;
    int*   csr_src = ws0 + off; off += (size_t)E;
    unsigned short* g1 = (unsigned short*)(ws0 + off); off += (size_t)n * 16;  // n*32 bf16
    unsigned short* g2 = (unsigned short*)(ws0 + off); off += (size_t)n * 8;   // n*16 bf16
    unsigned short* g3 = (unsigned short*)(ws0 + off); off += (size_t)n * 8;   // n*16 bf16
    unsigned short* W1T = (unsigned short*)(ws0 + off); off += 8192;           // 32x512 bf16
    int*   histG   = (int*)g1;  // alias: histG consumed by scan1 before g1 is written

    // ---- binning (hist overlapped with W conversion) ----
    hist_wconv<<<B + 32, 512, 0, stream>>>(dst, histG, W1, W1T, B, NB, E);
    scan1<<<nb_scan, 256, 0, stream>>>(histG, scanG, blksum, NBB);
    scan2<<<1, 256, 0, stream>>>(blksum, nb_scan);
    scatter_k<<<B, 512, 0, stream>>>(src, dst, scanG, blksum, pairs, B, NB, E);
    sort_bucket<<<NB, 512, 0, stream>>>(pairs, scanG, blksum, B, NB, csr_src, nstart, cnt, dis, n, E);

    // ---- layer-1 GEMM (dis ready -> scaled write), then fused gather chains ----
    gemm1_mfma<<<(n + 127) / 128, 512, 0, stream>>>(x, W1T, dis, g1, n);
    gather1<<<(n + 3) / 4, 256, 0, stream>>>(csr_src, nstart, cnt, g1, dis, b1, W2, g2, n);
    gather2<<<(n + 3) / 4, 256, 0, stream>>>(csr_src, nstart, cnt, g2, dis, b2, W3, g3, n);
    gather3<<<(n + 3) / 4, 256, 0, stream>>>(csr_src, nstart, cnt, g3, dis, b3, out, n);
}

// Round 18
// 281.595 us; speedup vs baseline: 1.0052x; 1.0052x over previous
//
#include <hip/hip_runtime.h>
#include <hip/hip_bf16.h>

// ---- bf16 helpers ----
static __device__ __forceinline__ unsigned short f2bf(float f) {
    unsigned u = __float_as_uint(f);
    unsigned r = (u + 0x7FFF + ((u >> 16) & 1)) >> 16;
    return (unsigned short)r;
}
static __device__ __forceinline__ float bflo(unsigned v) { return __uint_as_float(v << 16); }
static __device__ __forceinline__ float bfhi(unsigned v) { return __uint_as_float(v & 0xFFFF0000u); }
static __device__ __forceinline__ unsigned pack2bf(float a, float b) {
    __hip_bfloat162 h2 = __float22bfloat162_rn(float2{a, b});
    union { __hip_bfloat162 h; unsigned u; } cv;
    cv.h = h2;
    return cv.u;
}

typedef __attribute__((ext_vector_type(8))) short bf16x8;
typedef __attribute__((ext_vector_type(8))) unsigned short u16x8;
typedef __attribute__((ext_vector_type(4))) float f32x4;

// ==================== bucket binning ====================
#define BKT_SHIFT 7
#define BKT_NODES 128
#define CHUNK 16384  // edges per hist/scatter block -> B=196 blocks

__global__ __launch_bounds__(512) void hist_wconv(const int* __restrict__ dst, int* __restrict__ histG,
                                                  const float* __restrict__ W, unsigned short* __restrict__ W1T,
                                                  int B, int NB, int E) {
    if ((int)blockIdx.x >= B) {
        int gidx = (blockIdx.x - B) * 512 + threadIdx.x;
        if (gidx < 32 * 512) {
            int c = gidx >> 9, k = gidx & 511;
            W1T[gidx] = f2bf(W[(size_t)k * 32 + c]);
        }
        return;
    }
    __shared__ int hist[1024];
    int tid = threadIdx.x;
    for (int i = tid; i < NB; i += 512) hist[i] = 0;
    __syncthreads();
    int base = blockIdx.x * CHUNK;
    for (int i = tid; i < CHUNK; i += 512) {
        int e = base + i;
        if (e >= E) break;
        atomicAdd(&hist[dst[e] >> BKT_SHIFT], 1);
    }
    __syncthreads();
    for (int i = tid; i < NB; i += 512) histG[(size_t)i * B + blockIdx.x] = hist[i];
}

// scatter; blksum is RAW per-scanblock sums -> wave0 scans it locally (replaces scan2+scan3)
__global__ __launch_bounds__(512) void scatter_k(const int* __restrict__ src, const int* __restrict__ dst,
                                                 const int* __restrict__ scanG, const int* __restrict__ blksum,
                                                 int* __restrict__ pairs, int B, int NB, int E, int nbs) {
    __shared__ int sbase[1024];
    __shared__ int scnt[1024];
    __shared__ int bpref[128];
    int tid = threadIdx.x;
    if (tid < 64) {
        int c0 = (2 * tid < nbs) ? blksum[2 * tid] : 0;
        int c1 = (2 * tid + 1 < nbs) ? blksum[2 * tid + 1] : 0;
        int s = c0 + c1;
        #pragma unroll
        for (int off = 1; off < 64; off <<= 1) {
            int t = __shfl_up(s, off);
            if (tid >= off) s += t;
        }
        bpref[2 * tid]     = s - c1 - c0;
        bpref[2 * tid + 1] = s - c1;
    }
    __syncthreads();
    for (int i = tid; i < NB; i += 512) {
        size_t idx = (size_t)i * B + blockIdx.x;
        sbase[i] = scanG[idx] + bpref[idx >> 11];
        scnt[i] = 0;
    }
    __syncthreads();
    int base = blockIdx.x * CHUNK;
    for (int i = tid; i < CHUNK; i += 512) {
        int e = base + i;
        if (e >= E) break;
        int d = dst[e], s = src[e];
        int b = d >> BKT_SHIFT;
        int r = atomicAdd(&scnt[b], 1);
        pairs[sbase[b] + r] = (s << BKT_SHIFT) | (d & (BKT_NODES - 1));
    }
}

// ==================== scan (exclusive), 256 thr x 8 = 2048 elems/block ====================
#define SCAN_VPT 8
#define SCAN_ELEMS 2048

__global__ __launch_bounds__(256) void scan1(const int* __restrict__ in, int* __restrict__ out,
                                             int* __restrict__ blksum, int n) {
    __shared__ int sh[256];
    int base = blockIdx.x * SCAN_ELEMS + threadIdx.x * SCAN_VPT;
    int v[SCAN_VPT];
    int sum = 0;
    #pragma unroll
    for (int j = 0; j < SCAN_VPT; ++j) {
        v[j] = (base + j < n) ? in[base + j] : 0;
        sum += v[j];
    }
    sh[threadIdx.x] = sum;
    __syncthreads();
    for (int off = 1; off < 256; off <<= 1) {
        int t = (threadIdx.x >= off) ? sh[threadIdx.x - off] : 0;
        __syncthreads();
        sh[threadIdx.x] += t;
        __syncthreads();
    }
    if (threadIdx.x == 255) blksum[blockIdx.x] = sh[255];  // RAW block total
    int run = sh[threadIdx.x] - sum;
    #pragma unroll
    for (int j = 0; j < SCAN_VPT; ++j) {
        if (base + j < n) out[base + j] = run;
        run += v[j];
    }
}

// ==================== within-bucket counting sort -> CSR + nsc(start,cnt) + dis ====================
#define SORT_CAP 8192

__global__ __launch_bounds__(512) void sort_bucket(const int* __restrict__ pairs,
        const int* __restrict__ scanG, const int* __restrict__ blksum, int B, int NB,
        int* __restrict__ csr_src, int2* __restrict__ nsc,
        float* __restrict__ dis, int n, int E, int nbs) {
    __shared__ int keys[SORT_CAP];
    __shared__ int lcnt[BKT_NODES];
    __shared__ int lscan[BKT_NODES];
    __shared__ int lfill[BKT_NODES];
    __shared__ int bpref[128];
    int bkt = blockIdx.x, tid = threadIdx.x;
    if (tid < 64) {
        int c0 = (2 * tid < nbs) ? blksum[2 * tid] : 0;
        int c1 = (2 * tid + 1 < nbs) ? blksum[2 * tid + 1] : 0;
        int s = c0 + c1;
        #pragma unroll
        for (int off = 1; off < 64; off <<= 1) {
            int t = __shfl_up(s, off);
            if (tid >= off) s += t;
        }
        bpref[2 * tid]     = s - c1 - c0;
        bpref[2 * tid + 1] = s - c1;
    }
    if (tid < BKT_NODES) { lcnt[tid] = 0; lfill[tid] = 0; }
    __syncthreads();
    size_t idx0 = (size_t)bkt * B;
    int e0 = scanG[idx0] + bpref[idx0 >> 11];
    int e1 = E;
    if (bkt + 1 < NB) {
        size_t idx1 = (size_t)(bkt + 1) * B;
        e1 = scanG[idx1] + bpref[idx1 >> 11];
    }
    int m = e1 - e0;
    for (int i = tid; i < m; i += 512) {
        int k = pairs[e0 + i];
        if (i < SORT_CAP) keys[i] = k;
        atomicAdd(&lcnt[k & (BKT_NODES - 1)], 1);
    }
    __syncthreads();
    if (tid < 64) {
        int c0 = lcnt[2 * tid], c1 = lcnt[2 * tid + 1];
        int s = c0 + c1;
        #pragma unroll
        for (int off = 1; off < 64; off <<= 1) {
            int t = __shfl_up(s, off);
            if (tid >= off) s += t;
        }
        lscan[2 * tid]     = s - c1 - c0;
        lscan[2 * tid + 1] = s - c1;
    }
    __syncthreads();
    int nb0 = bkt << BKT_SHIFT;
    if (tid < BKT_NODES && nb0 + tid < n) {
        int deg = lcnt[tid];
        nsc[nb0 + tid] = make_int2(e0 + lscan[tid], deg);
        dis[nb0 + tid] = rsqrtf((float)deg + 1.0f);
    }
    for (int i = tid; i < m; i += 512) {
        int k = (i < SORT_CAP) ? keys[i] : pairs[e0 + i];
        int d = k & (BKT_NODES - 1);
        int pos = lscan[d] + atomicAdd(&lfill[d], 1);
        csr_src[e0 + pos] = k >> BKT_SHIFT;
    }
}

// ==================== gemm1 (MFMA): 512->32 bf16, 128 nodes/block, register-prefetch pipeline ====================

__global__ __launch_bounds__(512) void gemm1_mfma(const float* __restrict__ x, const unsigned short* __restrict__ W1T,
                                                  const float* __restrict__ dis, unsigned short* __restrict__ g, int n) {
    __shared__ __attribute__((aligned(16))) unsigned short wT[32][520];
    __shared__ __attribute__((aligned(16))) unsigned short xb[128][72];
    int tid = threadIdx.x;
    int node0 = blockIdx.x * 128;

    #pragma unroll
    for (int r = 0; r < 4; ++r) {
        int u8 = tid + r * 512;
        int c = u8 >> 6, kq = (u8 & 63) * 8;
        *(u16x8*)(&wT[c][kq]) = *(const u16x8*)(W1T + (size_t)c * 512 + kq);
    }

    int wv_ = tid >> 6;
    int lane = tid & 63;
    int mrow = lane & 15;
    int kg = lane >> 4;
    f32x4 acc0 = {0.f, 0.f, 0.f, 0.f};
    f32x4 acc1 = {0.f, 0.f, 0.f, 0.f};

    // staging geometry (fixed per thread)
    int snd[4], skq[4];
    const float* sptr[4];
    #pragma unroll
    for (int r = 0; r < 4; ++r) {
        int fi = tid + r * 512;
        snd[r] = fi >> 4;
        skq[r] = (fi & 15) * 4;
        int gn = min(node0 + snd[r], n - 1);
        sptr[r] = x + (size_t)gn * 512 + skq[r];
    }

    // preload chunk 0 into registers
    float4 ra[4];
    #pragma unroll
    for (int r = 0; r < 4; ++r) ra[r] = *(const float4*)(sptr[r]);

    for (int k0 = 0; k0 < 512; k0 += 64) {
        __syncthreads();   // xb consumed by previous iteration
        #pragma unroll
        for (int r = 0; r < 4; ++r) {
            uint2 pw;
            pw.x = pack2bf(ra[r].x, ra[r].y);
            pw.y = pack2bf(ra[r].z, ra[r].w);
            *(uint2*)(&xb[snd[r]][skq[r]]) = pw;
        }
        __syncthreads();   // xb ready
        if (k0 + 64 < 512) {
            #pragma unroll
            for (int r = 0; r < 4; ++r) ra[r] = *(const float4*)(sptr[r] + k0 + 64);
        }
        #pragma unroll
        for (int ks = 0; ks < 2; ++ks) {
            bf16x8 a  = *(const bf16x8*)(&xb[wv_ * 16 + mrow][ks * 32 + kg * 8]);
            bf16x8 b0 = *(const bf16x8*)(&wT[mrow][k0 + ks * 32 + kg * 8]);
            bf16x8 b1 = *(const bf16x8*)(&wT[16 + mrow][k0 + ks * 32 + kg * 8]);
            acc0 = __builtin_amdgcn_mfma_f32_16x16x32_bf16(a, b0, acc0, 0, 0, 0);
            acc1 = __builtin_amdgcn_mfma_f32_16x16x32_bf16(a, b1, acc1, 0, 0, 0);
        }
    }
    #pragma unroll
    for (int j = 0; j < 4; ++j) {
        int node = node0 + wv_ * 16 + kg * 4 + j;
        if (node < n) {
            float dv = dis[node];
            g[(size_t)node * 32 + mrow]      = f2bf(acc0[j] * dv);
            g[(size_t)node * 32 + 16 + mrow] = f2bf(acc1[j] * dv);
        }
    }
}

// ==================== gather1: uint2 CSR gather F=32 + fused (relu -> @W2 -> *dis) ====================

__global__ __launch_bounds__(256) void gather1(const int* __restrict__ csr_src,
        const int2* __restrict__ nsc,
        const unsigned short* __restrict__ g1, const float* __restrict__ dis,
        const float* __restrict__ b1, const float* __restrict__ W2,
        unsigned short* __restrict__ g2, int n) {
    __shared__ float w2t[16 * 33];
    for (int i = threadIdx.x; i < 512; i += 256) {
        int k = i >> 4, c = i & 15;
        w2t[c * 33 + k] = W2[i];
    }
    __syncthreads();
    int node = blockIdx.x * 4 + (threadIdx.x >> 6);
    if (node >= n) return;
    int lane = threadIdx.x & 63;
    int fq = lane & 7;
    int j = lane >> 3;
    int2 sc = nsc[node];
    int i0 = sc.x, i1 = sc.x + sc.y;
    float a0 = 0.f, a1 = 0.f, a2 = 0.f, a3 = 0.f;
    int i = i0 + j;
    for (; i + 24 < i1; i += 32) {
        int s1 = csr_src[i];
        int s2 = csr_src[i + 8];
        int s3 = csr_src[i + 16];
        int s4 = csr_src[i + 24];
        uint2 v1 = *(const uint2*)(g1 + (size_t)s1 * 32 + fq * 4);
        uint2 v2 = *(const uint2*)(g1 + (size_t)s2 * 32 + fq * 4);
        uint2 v3 = *(const uint2*)(g1 + (size_t)s3 * 32 + fq * 4);
        uint2 v4 = *(const uint2*)(g1 + (size_t)s4 * 32 + fq * 4);
        a0 += bflo(v1.x) + bflo(v2.x) + bflo(v3.x) + bflo(v4.x);
        a1 += bfhi(v1.x) + bfhi(v2.x) + bfhi(v3.x) + bfhi(v4.x);
        a2 += bflo(v1.y) + bflo(v2.y) + bflo(v3.y) + bflo(v4.y);
        a3 += bfhi(v1.y) + bfhi(v2.y) + bfhi(v3.y) + bfhi(v4.y);
    }
    for (; i < i1; i += 8) {
        uint2 v = *(const uint2*)(g1 + (size_t)csr_src[i] * 32 + fq * 4);
        a0 += bflo(v.x); a1 += bfhi(v.x);
        a2 += bflo(v.y); a3 += bfhi(v.y);
    }
    #pragma unroll
    for (int m = 8; m < 64; m <<= 1) {
        a0 += __shfl_xor(a0, m); a1 += __shfl_xor(a1, m);
        a2 += __shfl_xor(a2, m); a3 += __shfl_xor(a3, m);
    }
    float dv = dis[node];
    uint2 sv = *(const uint2*)(g1 + (size_t)node * 32 + fq * 4);
    float v0 = fmaxf((a0 + bflo(sv.x)) * dv + b1[4 * fq + 0], 0.f);
    float v1f = fmaxf((a1 + bfhi(sv.x)) * dv + b1[4 * fq + 1], 0.f);
    float v2f = fmaxf((a2 + bflo(sv.y)) * dv + b1[4 * fq + 2], 0.f);
    float v3f = fmaxf((a3 + bfhi(sv.y)) * dv + b1[4 * fq + 3], 0.f);
    int c = lane & 15;
    int j3 = lane >> 4;
    float p = 0.f;
    #pragma unroll
    for (int kk = 0; kk < 8; ++kk) {
        int k = j3 * 8 + kk;
        int srcl = k >> 2;
        float xk;
        if ((kk & 3) == 0) xk = __shfl(v0, srcl);
        else if ((kk & 3) == 1) xk = __shfl(v1f, srcl);
        else if ((kk & 3) == 2) xk = __shfl(v2f, srcl);
        else xk = __shfl(v3f, srcl);
        p = fmaf(xk, w2t[c * 33 + k], p);
    }
    p += __shfl_xor(p, 16);
    p += __shfl_xor(p, 32);
    if (lane < 16) g2[(size_t)node * 16 + c] = f2bf(p * dv);
}

// ==================== gather2: uint2 CSR gather F=16 + fused (relu -> @W3 -> *dis) ====================

__global__ __launch_bounds__(256) void gather2(const int* __restrict__ csr_src,
        const int2* __restrict__ nsc,
        const unsigned short* __restrict__ g2, const float* __restrict__ dis,
        const float* __restrict__ b2, const float* __restrict__ W3,
        unsigned short* __restrict__ g3, int n) {
    __shared__ float w3t[16 * 17];
    if (threadIdx.x < 256) {
        int k = threadIdx.x >> 4, c = threadIdx.x & 15;
        w3t[c * 17 + k] = (c < 11) ? W3[(size_t)k * 11 + c] : 0.f;
    }
    __syncthreads();
    int node = blockIdx.x * 4 + (threadIdx.x >> 6);
    if (node >= n) return;
    int lane = threadIdx.x & 63;
    int fq = lane & 3;
    int j = lane >> 2;
    int2 sc = nsc[node];
    int i0 = sc.x, i1 = sc.x + sc.y;
    float a0 = 0.f, a1 = 0.f, a2 = 0.f, a3 = 0.f;
    int i = i0 + j;
    for (; i + 16 < i1; i += 32) {
        int s1 = csr_src[i];
        int s2 = csr_src[i + 16];
        uint2 v1 = *(const uint2*)(g2 + (size_t)s1 * 16 + fq * 4);
        uint2 v2 = *(const uint2*)(g2 + (size_t)s2 * 16 + fq * 4);
        a0 += bflo(v1.x) + bflo(v2.x);
        a1 += bfhi(v1.x) + bfhi(v2.x);
        a2 += bflo(v1.y) + bflo(v2.y);
        a3 += bfhi(v1.y) + bfhi(v2.y);
    }
    if (i < i1) {
        uint2 v = *(const uint2*)(g2 + (size_t)csr_src[i] * 16 + fq * 4);
        a0 += bflo(v.x); a1 += bfhi(v.x);
        a2 += bflo(v.y); a3 += bfhi(v.y);
    }
    #pragma unroll
    for (int m = 4; m < 64; m <<= 1) {
        a0 += __shfl_xor(a0, m); a1 += __shfl_xor(a1, m);
        a2 += __shfl_xor(a2, m); a3 += __shfl_xor(a3, m);
    }
    float dv = dis[node];
    uint2 sv = *(const uint2*)(g2 + (size_t)node * 16 + fq * 4);
    float v0 = fmaxf((a0 + bflo(sv.x)) * dv + b2[4 * fq + 0], 0.f);
    float v1f = fmaxf((a1 + bfhi(sv.x)) * dv + b2[4 * fq + 1], 0.f);
    float v2f = fmaxf((a2 + bflo(sv.y)) * dv + b2[4 * fq + 2], 0.f);
    float v3f = fmaxf((a3 + bfhi(sv.y)) * dv + b2[4 * fq + 3], 0.f);
    int c = lane & 15;
    int j2 = lane >> 4;
    float p = 0.f;
    {
        float xk0 = __shfl(v0, j2);
        float xk1 = __shfl(v1f, j2);
        float xk2 = __shfl(v2f, j2);
        float xk3 = __shfl(v3f, j2);
        p = fmaf(xk0, w3t[c * 17 + j2 * 4 + 0], p);
        p = fmaf(xk1, w3t[c * 17 + j2 * 4 + 1], p);
        p = fmaf(xk2, w3t[c * 17 + j2 * 4 + 2], p);
        p = fmaf(xk3, w3t[c * 17 + j2 * 4 + 3], p);
    }
    p += __shfl_xor(p, 16);
    p += __shfl_xor(p, 32);
    if (lane < 16) g3[(size_t)node * 16 + c] = f2bf(p * dv);
}

// ==================== gather3: uint2 F=16 gather + self + bias + log_softmax ====================

__global__ __launch_bounds__(256) void gather3(const int* __restrict__ csr_src,
        const int2* __restrict__ nsc,
        const unsigned short* __restrict__ g, const float* __restrict__ dis,
        const float* __restrict__ bias, float* __restrict__ out, int n) {
    int node = blockIdx.x * 4 + (threadIdx.x >> 6);
    if (node >= n) return;
    int lane = threadIdx.x & 63;
    int fq = lane & 3;
    int j = lane >> 2;
    int2 sc = nsc[node];
    int i0 = sc.x, i1 = sc.x + sc.y;
    float a0 = 0.f, a1 = 0.f, a2 = 0.f, a3 = 0.f;
    int i = i0 + j;
    for (; i + 16 < i1; i += 32) {
        int s1 = csr_src[i];
        int s2 = csr_src[i + 16];
        uint2 v1 = *(const uint2*)(g + (size_t)s1 * 16 + fq * 4);
        uint2 v2 = *(const uint2*)(g + (size_t)s2 * 16 + fq * 4);
        a0 += bflo(v1.x) + bflo(v2.x);
        a1 += bfhi(v1.x) + bfhi(v2.x);
        a2 += bflo(v1.y) + bflo(v2.y);
        a3 += bfhi(v1.y) + bfhi(v2.y);
    }
    if (i < i1) {
        uint2 v = *(const uint2*)(g + (size_t)csr_src[i] * 16 + fq * 4);
        a0 += bflo(v.x); a1 += bfhi(v.x);
        a2 += bflo(v.y); a3 += bfhi(v.y);
    }
    #pragma unroll
    for (int m = 4; m < 64; m <<= 1) {
        a0 += __shfl_xor(a0, m); a1 += __shfl_xor(a1, m);
        a2 += __shfl_xor(a2, m); a3 += __shfl_xor(a3, m);
    }
    float dvn = dis[node];
    uint2 sv = *(const uint2*)(g + (size_t)node * 16 + fq * 4);
    int f0 = 4 * fq;
    bool ok0 = f0 + 0 < 11, ok1 = f0 + 1 < 11, ok2 = f0 + 2 < 11, ok3 = f0 + 3 < 11;
    float v0 = (a0 + bflo(sv.x)) * dvn + (ok0 ? bias[f0 + 0] : 0.f);
    float v1f = (a1 + bfhi(sv.x)) * dvn + (ok1 ? bias[f0 + 1] : 0.f);
    float v2f = (a2 + bflo(sv.y)) * dvn + (ok2 ? bias[f0 + 2] : 0.f);
    float v3f = (a3 + bfhi(sv.y)) * dvn + (ok3 ? bias[f0 + 3] : 0.f);
    const float NEG = -3.0e38f;
    float m0 = fmaxf(fmaxf(ok0 ? v0 : NEG, ok1 ? v1f : NEG),
                     fmaxf(ok2 ? v2f : NEG, ok3 ? v3f : NEG));
    m0 = fmaxf(m0, __shfl_xor(m0, 1));
    m0 = fmaxf(m0, __shfl_xor(m0, 2));
    float s = (ok0 ? __expf(v0 - m0) : 0.f) + (ok1 ? __expf(v1f - m0) : 0.f)
            + (ok2 ? __expf(v2f - m0) : 0.f) + (ok3 ? __expf(v3f - m0) : 0.f);
    s += __shfl_xor(s, 1);
    s += __shfl_xor(s, 2);
    float ls = __logf(s) + m0;
    if (lane < 4) {
        float* orow = out + (size_t)node * 11 + f0;
        if (ok0) orow[0] = v0 - ls;
        if (ok1) orow[1] = v1f - ls;
        if (ok2) orow[2] = v2f - ls;
        if (ok3) orow[3] = v3f - ls;
    }
}

// ==================== launch ====================

extern "C" void kernel_launch(void* const* d_in, const int* in_sizes, int n_in,
                              void* d_out, int out_size, void* d_ws, size_t ws_size,
                              hipStream_t stream) {
    const float* x  = (const float*)d_in[0];
    const int*   ei = (const int*)d_in[1];
    const float* W1 = (const float*)d_in[2];
    const float* b1 = (const float*)d_in[3];
    const float* W2 = (const float*)d_in[4];
    const float* b2 = (const float*)d_in[5];
    const float* W3 = (const float*)d_in[6];
    const float* b3 = (const float*)d_in[7];
    float* out = (float*)d_out;

    const int n = in_sizes[0] / 512;
    const int E = in_sizes[1] / 2;
    const int* src = ei;
    const int* dst = ei + E;

    const int NB = (n + BKT_NODES - 1) >> BKT_SHIFT;      // 782
    const int B  = (E + CHUNK - 1) / CHUNK;               // 196
    const int NBB = NB * B;
    const int nb_scan = (NBB + SCAN_ELEMS - 1) / SCAN_ELEMS;  // 75 (<=128 required)

    // workspace layout (4B elements)
    int* ws0 = (int*)d_ws;
    size_t off = 0;
    float* dis     = (float*)(ws0 + off); off += (size_t)n;
    int2*  nsc     = (int2*)(ws0 + off);  off += (size_t)2 * n;
    int*   scanG   = ws0 + off; off += (size_t)NBB;
    int*   blksum  = ws0 + off; off += 256;
    int*   pairs   = ws0 + off; off += (size_t)E;
    int*   csr_src = ws0 + off; off += (size_t)E;
    unsigned short* g1 = (unsigned short*)(ws0 + off); off += (size_t)n * 16;  // n*32 bf16
    unsigned short* g2 = (unsigned short*)(ws0 + off); off += (size_t)n * 8;   // n*16 bf16
    unsigned short* g3 = (unsigned short*)(ws0 + off); off += (size_t)n * 8;   // n*16 bf16
    unsigned short* W1T = (unsigned short*)(ws0 + off); off += 8192;           // 32x512 bf16
    int*   histG   = (int*)g1;  // alias: histG consumed by scan1 before g1 is written

    // ---- binning (hist overlapped with W conversion) ----
    hist_wconv<<<B + 32, 512, 0, stream>>>(dst, histG, W1, W1T, B, NB, E);
    scan1<<<nb_scan, 256, 0, stream>>>(histG, scanG, blksum, NBB);
    scatter_k<<<B, 512, 0, stream>>>(src, dst, scanG, blksum, pairs, B, NB, E, nb_scan);
    sort_bucket<<<NB, 512, 0, stream>>>(pairs, scanG, blksum, B, NB, csr_src, nsc, dis, n, E, nb_scan);

    // ---- layer-1 GEMM (register-prefetch pipeline), then fused gather chains ----
    gemm1_mfma<<<(n + 127) / 128, 512, 0, stream>>>(x, W1T, dis, g1, n);
    gather1<<<(n + 3) / 4, 256, 0, stream>>>(csr_src, nsc, g1, dis, b1, W2, g2, n);
    gather2<<<(n + 3) / 4, 256, 0, stream>>>(csr_src, nsc, g2, dis, b2, W3, g3, n);
    gather3<<<(n + 3) / 4, 256, 0, stream>>>(csr_src, nsc, g3, dis, b3, out, n);
}